// Round 1
// baseline (5202.563 us; speedup 1.0000x reference)
//
#include <hip/hip_runtime.h>
#include <math.h>

#define B_ 256
#define T_ 2048
#define D_ 128
#define H_ 128
#define G_ 512
#define CHUNK 16

// Pre-kernel: W_ihT[d][g] = W_ih[g][d]  (makes per-d weight reads lane-coalesced)
__global__ void transpose_wih(const float* __restrict__ W_ih,
                              float* __restrict__ W_ihT) {
    int o = blockIdx.x * blockDim.x + threadIdx.x;  // 65536 threads
    int d = o >> 9;        // 0..127
    int g = o & 511;       // 0..511
    W_ihT[o] = W_ih[g * D_ + d];
}

__device__ __forceinline__ float sigmoidf_(float x) {
    return 1.0f / (1.0f + __expf(-x));
}

__launch_bounds__(512, 2)
__global__ void att_lstm_main(const float* __restrict__ x,      // [B,T,D]
                              const float* __restrict__ W_hh,   // [4H,H]
                              const float* __restrict__ W_ihT,  // [D,4H]
                              const float* __restrict__ b_ih,   // [4H]
                              const float* __restrict__ b_hh,   // [4H]
                              float* __restrict__ h_states,     // ws [B,T,H]
                              float* __restrict__ out) {        // [B,H]
    const int b   = blockIdx.x;
    const int tid = threadIdx.x;
    const int g   = tid;  // gate row owned by this thread

    __shared__ float x_lds[CHUNK][D_];   // 8 KB
    __shared__ float h_lds[H_];          // 512 B
    __shared__ float gates_lds[G_];      // 2 KB
    __shared__ float sc[T_];             // 8 KB (scores -> exp weights)
    __shared__ float red[16];            // cross-wave reductions
    __shared__ float part[4][H_];        // 2 KB partial outputs

    // ---- load this thread's W_hh row into registers (stays resident) ----
    float whh[D_];
    {
        const float4* wr = (const float4*)(W_hh + (size_t)g * H_);
        #pragma unroll
        for (int i = 0; i < D_ / 4; i++) {
            float4 w = wr[i];
            whh[4*i+0] = w.x; whh[4*i+1] = w.y;
            whh[4*i+2] = w.z; whh[4*i+3] = w.w;
        }
    }
    const float bias = b_ih[g] + b_hh[g];

    if (tid < H_) h_lds[tid] = 0.0f;
    float c_reg = 0.0f;
    __syncthreads();

    const float* xb = x + (size_t)b * T_ * D_;
    float* hs = h_states + (size_t)b * T_ * H_;

    // =================== LSTM scan ===================
    for (int t0 = 0; t0 < T_; t0 += CHUNK) {
        // stage x chunk: 16*128 floats = 512 float4s, one per thread
        ((float4*)x_lds)[tid] = ((const float4*)(xb + (size_t)t0 * D_))[tid];
        __syncthreads();

        // input projection for the chunk: acc[tt] = sum_d W_ih[g][d]*x[t0+tt][d]
        float acc[CHUNK];
        #pragma unroll
        for (int tt = 0; tt < CHUNK; tt++) acc[tt] = 0.0f;

        for (int db = 0; db < D_ / 8; db++) {   // 16 blocks of 8 d's
            const int d0 = db * 8;
            float w0 = W_ihT[(d0+0)*G_ + g];
            float w1 = W_ihT[(d0+1)*G_ + g];
            float w2 = W_ihT[(d0+2)*G_ + g];
            float w3 = W_ihT[(d0+3)*G_ + g];
            float w4 = W_ihT[(d0+4)*G_ + g];
            float w5 = W_ihT[(d0+5)*G_ + g];
            float w6 = W_ihT[(d0+6)*G_ + g];
            float w7 = W_ihT[(d0+7)*G_ + g];
            #pragma unroll
            for (int tt = 0; tt < CHUNK; tt++) {
                const float4 xa = ((const float4*)&x_lds[tt][d0])[0];
                const float4 xv = ((const float4*)&x_lds[tt][d0])[1];
                acc[tt] += w0*xa.x + w1*xa.y + w2*xa.z + w3*xa.w
                         + w4*xv.x + w5*xv.y + w6*xv.z + w7*xv.w;
            }
        }

        // 16 recurrence steps
        #pragma unroll 1
        for (int tt = 0; tt < CHUNK; tt++) {
            float s0 = acc[tt] + bias, s1 = 0.f, s2 = 0.f, s3 = 0.f;
            const float4* hp = (const float4*)h_lds;
            #pragma unroll
            for (int db = 0; db < H_ / 16; db++) {  // 8 iters
                float4 h0 = hp[db*4+0], h1 = hp[db*4+1];
                float4 h2 = hp[db*4+2], h3 = hp[db*4+3];
                s0 += whh[db*16+ 0]*h0.x + whh[db*16+ 1]*h0.y + whh[db*16+ 2]*h0.z + whh[db*16+ 3]*h0.w;
                s1 += whh[db*16+ 4]*h1.x + whh[db*16+ 5]*h1.y + whh[db*16+ 6]*h1.z + whh[db*16+ 7]*h1.w;
                s2 += whh[db*16+ 8]*h2.x + whh[db*16+ 9]*h2.y + whh[db*16+10]*h2.z + whh[db*16+11]*h2.w;
                s3 += whh[db*16+12]*h3.x + whh[db*16+13]*h3.y + whh[db*16+14]*h3.z + whh[db*16+15]*h3.w;
            }
            gates_lds[g] = (s0 + s1) + (s2 + s3);
            __syncthreads();
            float hv = 0.f;
            if (tid < H_) {
                float iv = gates_lds[tid];
                float fv = gates_lds[tid + 128];
                float gv = gates_lds[tid + 256];
                float ov = gates_lds[tid + 384];
                float ig = sigmoidf_(iv), fg = sigmoidf_(fv);
                float gt = tanhf(gv),     og = sigmoidf_(ov);
                c_reg = fg * c_reg + ig * gt;
                hv = og * tanhf(c_reg);
                h_lds[tid] = hv;
            }
            __syncthreads();
            // store after barrier: next barrier's vmcnt drain gives it slack
            if (tid < H_) hs[(size_t)(t0 + tt) * H_ + tid] = hv;
        }
    }
    __syncthreads();  // make final-chunk h stores visible in-block

    // =================== attention pooling ===================
    // h_last is in h_lds. 1) scores
    const float4* hl4 = (const float4*)h_lds;
    #pragma unroll 1
    for (int q = 0; q < 4; q++) {
        const int t = q * 512 + tid;
        const float4* hr = (const float4*)(hs + (size_t)t * H_);
        float a0 = 0.f, a1 = 0.f, a2 = 0.f, a3 = 0.f;
        #pragma unroll
        for (int i = 0; i < H_ / 16; i++) {
            float4 r0 = hr[i*4+0], l0 = hl4[i*4+0];
            float4 r1 = hr[i*4+1], l1 = hl4[i*4+1];
            float4 r2 = hr[i*4+2], l2 = hl4[i*4+2];
            float4 r3 = hr[i*4+3], l3 = hl4[i*4+3];
            a0 += r0.x*l0.x + r0.y*l0.y + r0.z*l0.z + r0.w*l0.w;
            a1 += r1.x*l1.x + r1.y*l1.y + r1.z*l1.z + r1.w*l1.w;
            a2 += r2.x*l2.x + r2.y*l2.y + r2.z*l2.z + r2.w*l2.w;
            a3 += r3.x*l3.x + r3.y*l3.y + r3.z*l3.z + r3.w*l3.w;
        }
        sc[t] = (a0 + a1) + (a2 + a3);
    }

    // 2) softmax denominators (each thread touches only its own 4 entries)
    float m = -3.0e38f;
    #pragma unroll
    for (int q = 0; q < 4; q++) m = fmaxf(m, sc[q * 512 + tid]);
    #pragma unroll
    for (int off = 1; off < 64; off <<= 1) m = fmaxf(m, __shfl_xor(m, off));
    if ((tid & 63) == 0) red[tid >> 6] = m;
    __syncthreads();
    float mx = red[0];
    #pragma unroll
    for (int w = 1; w < 8; w++) mx = fmaxf(mx, red[w]);

    float ssum = 0.f;
    #pragma unroll
    for (int q = 0; q < 4; q++) {
        float e = __expf(sc[q * 512 + tid] - mx);
        sc[q * 512 + tid] = e;
        ssum += e;
    }
    #pragma unroll
    for (int off = 1; off < 64; off <<= 1) ssum += __shfl_xor(ssum, off);
    if ((tid & 63) == 0) red[8 + (tid >> 6)] = ssum;
    __syncthreads();
    float tot = 0.f;
    #pragma unroll
    for (int w = 0; w < 8; w++) tot += red[8 + w];
    const float inv = 1.0f / tot;

    // 3) weighted sum: out[j] = inv * sum_t e_t * h[t][j]  (coalesced reads)
    {
        const int j = tid & 127;
        const int q = tid >> 7;   // 0..3
        const float* hp = hs + (size_t)q * 512 * H_ + j;
        const float* scp = sc + q * 512;
        float a0 = 0.f, a1 = 0.f, a2 = 0.f, a3 = 0.f;
        #pragma unroll 4
        for (int t = 0; t < 512; t += 4) {
            a0 += scp[t+0] * hp[(size_t)(t+0) * H_];
            a1 += scp[t+1] * hp[(size_t)(t+1) * H_];
            a2 += scp[t+2] * hp[(size_t)(t+2) * H_];
            a3 += scp[t+3] * hp[(size_t)(t+3) * H_];
        }
        part[q][j] = (a0 + a1) + (a2 + a3);
    }
    __syncthreads();
    if (tid < H_) {
        out[(size_t)b * H_ + tid] =
            (part[0][tid] + part[1][tid] + part[2][tid] + part[3][tid]) * inv;
    }
}

extern "C" void kernel_launch(void* const* d_in, const int* in_sizes, int n_in,
                              void* d_out, int out_size, void* d_ws, size_t ws_size,
                              hipStream_t stream) {
    const float* x    = (const float*)d_in[0];
    const float* W_ih = (const float*)d_in[1];
    const float* W_hh = (const float*)d_in[2];
    const float* b_ih = (const float*)d_in[3];
    const float* b_hh = (const float*)d_in[4];
    float* out = (float*)d_out;

    float* h_states = (float*)d_ws;  // B*T*H fp32 = 256 MB
    float* W_ihT = (float*)((char*)d_ws + (size_t)B_ * T_ * H_ * sizeof(float));

    transpose_wih<<<256, 256, 0, stream>>>(W_ih, W_ihT);
    att_lstm_main<<<B_, 512, 0, stream>>>(x, W_hh, W_ihT, b_ih, b_hh,
                                          h_states, out);
}

// Round 3
// 1814.149 us; speedup vs baseline: 2.8678x; 2.8678x over previous
//
#include <hip/hip_runtime.h>
#include <math.h>

#define B_ 256
#define T_ 2048
#define D_ 128
#define H_ 128
#define CHUNK 16
#define NCHUNK (T_ / CHUNK)
#define XPITCH 136   // f16 elems per x_lds row: 128 + 8 pad -> 272 B, 16B-aligned

typedef _Float16 f16;
typedef __attribute__((ext_vector_type(8))) _Float16 f16x8;
typedef __attribute__((ext_vector_type(4))) _Float16 f16x4;
typedef __attribute__((ext_vector_type(2))) _Float16 f16x2;
typedef __attribute__((ext_vector_type(4))) float f32x4;

__device__ __forceinline__ float sigf(float x) { return 1.0f / (1.0f + __expf(-x)); }
__device__ __forceinline__ float tanh_fast(float x) {
    // tanh(x) = 1 - 2/(1+e^{2x}); graceful at +/-inf (exp->0 or inf)
    return 1.0f - 2.0f / (1.0f + __expf(2.0f * x));
}

// ============================ LSTM scan ============================
// grid = 256 (one batch element per block), block = 512 (8 waves)
// wave w owns gate tiles {q*128 + [16w,16w+16)} for q = 0..3 (i,f,g,o)
__global__ __launch_bounds__(512, 2)
void lstm_scan(const float* __restrict__ x,      // [B,T,D]
               const float* __restrict__ W_ih,   // [4H,D]
               const float* __restrict__ W_hh,   // [4H,H]
               const float* __restrict__ b_ih,   // [4H]
               const float* __restrict__ b_hh,   // [4H]
               float* __restrict__ h_states) {   // ws [B,T,H]
    const int b   = blockIdx.x;
    const int tid = threadIdx.x;
    const int w   = tid >> 6;      // wave 0..7
    const int l   = tid & 63;      // lane
    const int l15 = l & 15;
    const int lg  = l >> 4;        // k-group 0..3
    const int jw  = (w << 4) | l15;  // hidden index j owned by this lane, 0..127

    __shared__ __align__(16) f16   h2[2][H_];               // 2 x 256 B
    __shared__ __align__(16) f16   x_lds[CHUNK][XPITCH];    // 4.25 KB
    __shared__ __align__(16) float proj_lds[CHUNK][H_][4];  // 32 KB  [t][j][gate]

    // ---- resident weight B-fragments (f16): lane holds W[q*128+jw][kk*32+lg*8+e]
    f16x8 wbh[4][4];  // [gate q][k-tile kk]  W_hh
    f16x8 wbi[4][4];  //                      W_ih
    float bias[4];
    #pragma unroll
    for (int q = 0; q < 4; q++) {
        const int g = q * H_ + jw;
        bias[q] = b_ih[g] + b_hh[g];
        #pragma unroll
        for (int kk = 0; kk < 4; kk++) {
            const float* ph = W_hh + (size_t)g * H_ + kk * 32 + lg * 8;
            const float* pi = W_ih + (size_t)g * D_ + kk * 32 + lg * 8;
            f16x8 vh, vi;
            #pragma unroll
            for (int e = 0; e < 8; e++) { vh[e] = (f16)ph[e]; vi[e] = (f16)pi[e]; }
            wbh[q][kk] = vh; wbi[q][kk] = vi;
        }
    }

    if (tid < 64) ((unsigned int*)&h2[0][0])[tid] = 0u;  // h0 = 0

    const float* xb = x + (size_t)b * T_ * D_;
    float* hs = h_states + (size_t)b * T_ * H_;

    // prefetch chunk 0 (16 t x 128 d = 512 float4, one per thread)
    float4 xpre = ((const float4*)xb)[tid];

    float cst = 0.0f;    // cell state for j = jw (replicated across lg groups)
    float h_prev = 0.0f; // last computed h (stored one step late)

    for (int c = 0; c < NCHUNK; c++) {
        // ---- stage x chunk to LDS (f16) ----
        {
            const int ts = tid >> 5;          // 0..15
            const int d0 = (tid & 31) * 4;    // 0..124
            f16x4 pk;
            pk[0] = (f16)xpre.x; pk[1] = (f16)xpre.y;
            pk[2] = (f16)xpre.z; pk[3] = (f16)xpre.w;
            *(f16x4*)&x_lds[ts][d0] = pk;
        }
        __syncthreads();

        // prefetch next chunk while proj runs
        if (c + 1 < NCHUNK)
            xpre = ((const float4*)(xb + (size_t)(c + 1) * CHUNK * D_))[tid];

        // ---- input projection for the chunk: [16,128] x [128,512] ----
        f32x4 pacc[4] = {{0,0,0,0},{0,0,0,0},{0,0,0,0},{0,0,0,0}};
        {
            f16x8 ax[4];
            #pragma unroll
            for (int kk = 0; kk < 4; kk++)
                ax[kk] = *(const f16x8*)&x_lds[l15][kk * 32 + lg * 8];
            #pragma unroll
            for (int q = 0; q < 4; q++)
                #pragma unroll
                for (int kk = 0; kk < 4; kk++)
                    pacc[q] = __builtin_amdgcn_mfma_f32_16x16x32_f16(
                        ax[kk], wbi[q][kk], pacc[q], 0, 0, 0);
        }
        // scatter proj to LDS: row t = lg*4+r, entry [t][jw][q]
        #pragma unroll
        for (int r = 0; r < 4; r++) {
            f32x4 row = { pacc[0][r], pacc[1][r], pacc[2][r], pacc[3][r] };
            *(f32x4*)&proj_lds[lg * 4 + r][jw][0] = row;
        }
        __syncthreads();

        // ---- 16 recurrence steps ----
        #pragma unroll 4
        for (int tt = 0; tt < CHUNK; tt++) {
            const int t = c * CHUNK + tt;
            // store previous step's h early (vmcnt slack before the barrier)
            if (t > 0 && lg == 0) hs[(size_t)(t - 1) * H_ + jw] = h_prev;

            const f32x4 seed4 = *(const f32x4*)&proj_lds[tt][jw][0];

            // A-fragment of h: address ignores l15 -> all 16 rows identical
            f16x8 ah[4];
            const f16* hb = h2[tt & 1];
            #pragma unroll
            for (int kk = 0; kk < 4; kk++)
                ah[kk] = *(const f16x8*)&hb[kk * 32 + lg * 8];

            f32x4 acc[4];
            #pragma unroll
            for (int q = 0; q < 4; q++) {
                const float s = seed4[q] + bias[q];
                f32x4 cc = { s, s, s, s };
                #pragma unroll
                for (int kk = 0; kk < 4; kk++)
                    cc = __builtin_amdgcn_mfma_f32_16x16x32_f16(
                        ah[kk], wbh[q][kk], cc, 0, 0, 0);
                acc[q] = cc;
            }
            // every lane holds gates for j = jw (rows replicated)
            const float ig = sigf(acc[0][0]);
            const float fg = sigf(acc[1][0]);
            const float gt = tanh_fast(acc[2][0]);
            const float og = sigf(acc[3][0]);
            cst = fg * cst + ig * gt;
            const float h = og * tanh_fast(cst);
            h_prev = h;

            // publish h (f16 pairs) into the other buffer
            const float hn = __shfl_xor(h, 1);
            if (lg == 0 && (l15 & 1) == 0) {
                f16x2 pr; pr[0] = (f16)h; pr[1] = (f16)hn;
                *(f16x2*)&h2[(tt + 1) & 1][jw] = pr;   // jw even -> 4B aligned
            }
            __syncthreads();
        }
    }
    if (lg == 0) hs[(size_t)(T_ - 1) * H_ + jw] = h_prev;
}

// ============================ attention ============================
__global__ __launch_bounds__(512)
void attention(const float* __restrict__ h_states,  // [B,T,H]
               float* __restrict__ out) {           // [B,H]
    const int b   = blockIdx.x;
    const int tid = threadIdx.x;

    __shared__ float h_lds[H_];
    __shared__ float sc[T_];
    __shared__ float red[16];
    __shared__ float part[4][H_];

    const float* hs = h_states + (size_t)b * T_ * H_;
    if (tid < H_) h_lds[tid] = hs[(size_t)(T_ - 1) * H_ + tid];
    __syncthreads();

    // 1) scores
    const float4* hl4 = (const float4*)h_lds;
    #pragma unroll 1
    for (int q = 0; q < 4; q++) {
        const int t = q * 512 + tid;
        const float4* hr = (const float4*)(hs + (size_t)t * H_);
        float a0 = 0.f, a1 = 0.f, a2 = 0.f, a3 = 0.f;
        #pragma unroll
        for (int i = 0; i < H_ / 16; i++) {
            float4 r0 = hr[i*4+0], l0 = hl4[i*4+0];
            float4 r1 = hr[i*4+1], l1 = hl4[i*4+1];
            float4 r2 = hr[i*4+2], l2 = hl4[i*4+2];
            float4 r3 = hr[i*4+3], l3 = hl4[i*4+3];
            a0 += r0.x*l0.x + r0.y*l0.y + r0.z*l0.z + r0.w*l0.w;
            a1 += r1.x*l1.x + r1.y*l1.y + r1.z*l1.z + r1.w*l1.w;
            a2 += r2.x*l2.x + r2.y*l2.y + r2.z*l2.z + r2.w*l2.w;
            a3 += r3.x*l3.x + r3.y*l3.y + r3.z*l3.z + r3.w*l3.w;
        }
        sc[t] = (a0 + a1) + (a2 + a3);
    }

    // 2) softmax over T
    float m = -3.0e38f;
    #pragma unroll
    for (int q = 0; q < 4; q++) m = fmaxf(m, sc[q * 512 + tid]);
    #pragma unroll
    for (int off = 1; off < 64; off <<= 1) m = fmaxf(m, __shfl_xor(m, off));
    if ((tid & 63) == 0) red[tid >> 6] = m;
    __syncthreads();
    float mx = red[0];
    #pragma unroll
    for (int w2 = 1; w2 < 8; w2++) mx = fmaxf(mx, red[w2]);

    float ssum = 0.f;
    #pragma unroll
    for (int q = 0; q < 4; q++) {
        float e = __expf(sc[q * 512 + tid] - mx);
        sc[q * 512 + tid] = e;
        ssum += e;
    }
    #pragma unroll
    for (int off = 1; off < 64; off <<= 1) ssum += __shfl_xor(ssum, off);
    if ((tid & 63) == 0) red[8 + (tid >> 6)] = ssum;
    __syncthreads();
    float tot = 0.f;
    #pragma unroll
    for (int w2 = 0; w2 < 8; w2++) tot += red[8 + w2];
    const float inv = 1.0f / tot;

    // 3) weighted sum
    {
        const int j = tid & 127;
        const int q = tid >> 7;
        const float* hp  = hs + (size_t)q * 512 * H_ + j;
        const float* scp = sc + q * 512;
        float a0 = 0.f, a1 = 0.f, a2 = 0.f, a3 = 0.f;
        #pragma unroll 4
        for (int t = 0; t < 512; t += 4) {
            a0 += scp[t+0] * hp[(size_t)(t+0) * H_];
            a1 += scp[t+1] * hp[(size_t)(t+1) * H_];
            a2 += scp[t+2] * hp[(size_t)(t+2) * H_];
            a3 += scp[t+3] * hp[(size_t)(t+3) * H_];
        }
        part[q][j] = (a0 + a1) + (a2 + a3);
    }
    __syncthreads();
    if (tid < H_) {
        out[(size_t)b * H_ + tid] =
            (part[0][tid] + part[1][tid] + part[2][tid] + part[3][tid]) * inv;
    }
}

extern "C" void kernel_launch(void* const* d_in, const int* in_sizes, int n_in,
                              void* d_out, int out_size, void* d_ws, size_t ws_size,
                              hipStream_t stream) {
    const float* x    = (const float*)d_in[0];
    const float* W_ih = (const float*)d_in[1];
    const float* W_hh = (const float*)d_in[2];
    const float* b_ih = (const float*)d_in[3];
    const float* b_hh = (const float*)d_in[4];
    float* out = (float*)d_out;

    float* h_states = (float*)d_ws;  // B*T*H fp32 = 256 MB

    lstm_scan<<<B_, 512, 0, stream>>>(x, W_ih, W_hh, b_ih, b_hh, h_states);
    attention<<<B_, 512, 0, stream>>>(h_states, out);
}

// Round 4
// 1705.151 us; speedup vs baseline: 3.0511x; 1.0639x over previous
//
#include <hip/hip_runtime.h>
#include <math.h>

#define B_ 256
#define T_ 2048
#define D_ 128
#define H_ 128
#define CHUNK 16
#define NCHUNK (T_ / CHUNK)
#define XPITCH 136   // f16 elems per x_lds row: 128 + 8 pad (272 B = 17*16, 16B-aligned rows)

typedef _Float16 f16;
typedef __attribute__((ext_vector_type(8))) _Float16 f16x8;
typedef __attribute__((ext_vector_type(4))) _Float16 f16x4;
typedef __attribute__((ext_vector_type(2))) _Float16 f16x2;
typedef __attribute__((ext_vector_type(4))) float f32x4;
typedef __attribute__((ext_vector_type(2))) float f32x2;

__device__ __forceinline__ float sigf(float x) { return 1.0f / (1.0f + __expf(-x)); }
__device__ __forceinline__ float tanh_fast(float x) {
    return 1.0f - 2.0f / (1.0f + __expf(2.0f * x));  // graceful at +/-inf
}

// ======================= weight pre-pack =======================
// frag layout (per matrix): flat index r = (w*16 + q*4 + kk)*64 + l, 8 f16 each:
//   elem e = W[q*128 + w*16 + (l&15)][kk*32 + (l>>4)*8 + e]
__global__ void pack_weights(const float* __restrict__ W_ih,
                             const float* __restrict__ W_hh,
                             f16* __restrict__ pih, f16* __restrict__ phh) {
    const int idx = blockIdx.x * 256 + threadIdx.x;  // 0..16383
    const int m = idx >> 13;          // 0: ih, 1: hh
    const int r = idx & 8191;
    const int w  = r >> 10;
    const int q  = (r >> 8) & 3;
    const int kk = (r >> 6) & 3;
    const int l  = r & 63;
    const int g  = q * 128 + w * 16 + (l & 15);
    const int k0 = kk * 32 + (l >> 4) * 8;
    const float* src = (m ? W_hh : W_ih) + (size_t)g * 128 + k0;
    f16* dst = (m ? phh : pih) + (size_t)r * 8;
    f16x8 v;
    #pragma unroll
    for (int e = 0; e < 8; e++) v[e] = (f16)src[e];
    *(f16x8*)dst = v;
}

// ============================ LSTM scan ============================
// grid = 256 (one batch element per block), block = 512 (8 waves)
// wave w owns j in [16w,16w+16); lane = jw = w*16 + (l&15); lg = k-group
__global__ __launch_bounds__(512, 2)
void lstm_scan(const float* __restrict__ x,      // [B,T,D]
               const f16* __restrict__ pih,      // packed W_ih frags
               const f16* __restrict__ phh,      // packed W_hh frags
               const float* __restrict__ b_ih,   // [4H]
               const float* __restrict__ b_hh,   // [4H]
               f16* __restrict__ h_states) {     // ws [B,T,H] f16
    const int b   = blockIdx.x;
    const int tid = threadIdx.x;
    const int w   = tid >> 6;
    const int l   = tid & 63;
    const int l15 = l & 15;
    const int lg  = l >> 4;
    const int jw  = (w << 4) | l15;

    __shared__ __align__(16) f16   h2[2][H_];               // 512 B
    __shared__ __align__(16) f16   x_lds[CHUNK][XPITCH];    // 4.25 KB
    __shared__ __align__(16) f16   hbuf[CHUNK][H_];         // 4 KB
    __shared__ __align__(16) float proj_lds[CHUNK][H_][4];  // 32 KB

    // ---- resident W_hh fragments (64 VGPRs) ----
    f16x8 wbh[4][4];
    {
        const f16x8* ph = (const f16x8*)phh;
        #pragma unroll
        for (int q = 0; q < 4; q++)
            #pragma unroll
            for (int kk = 0; kk < 4; kk++)
                wbh[q][kk] = ph[(w * 16 + q * 4 + kk) * 64 + l];
    }
    float bias[4];
    #pragma unroll
    for (int q = 0; q < 4; q++) bias[q] = b_ih[q * 128 + jw] + b_hh[q * 128 + jw];

    if (tid < 64) ((unsigned int*)&h2[0][0])[tid] = 0u;  // h0 = 0

    const float* xb = x + (size_t)b * T_ * D_;
    f16* hs = h_states + (size_t)b * T_ * H_;

    float4 xpre = ((const float4*)xb)[tid];  // prefetch chunk 0
    float cst = 0.0f;

    for (int c = 0; c < NCHUNK; c++) {
        // ---- issue this chunk's W_ih fragment loads (L2-resident) ----
        f16x8 wbi[4][4];
        {
            const f16x8* pi = (const f16x8*)pih;
            #pragma unroll
            for (int q = 0; q < 4; q++)
                #pragma unroll
                for (int kk = 0; kk < 4; kk++)
                    wbi[q][kk] = pi[(w * 16 + q * 4 + kk) * 64 + l];
        }

        // ---- read prev chunk's hbuf (LDS) for batched store ----
        f16x4 hb;
        if (c > 0) hb = ((const f16x4*)hbuf)[tid];

        // ---- stage x chunk to LDS (f16) ----
        {
            const int ts = tid >> 5;
            const int d0 = (tid & 31) * 4;
            f16x4 pk;
            pk[0] = (f16)xpre.x; pk[1] = (f16)xpre.y;
            pk[2] = (f16)xpre.z; pk[3] = (f16)xpre.w;
            *(f16x4*)&x_lds[ts][d0] = pk;
        }
        __syncthreads();

        // batched h store for chunk c-1 (coalesced, fire & forget)
        if (c > 0)
            *(f16x4*)(hs + (size_t)(c - 1) * CHUNK * H_ + (size_t)tid * 4) = hb;

        // prefetch next x chunk
        if (c + 1 < NCHUNK)
            xpre = ((const float4*)(xb + (size_t)(c + 1) * CHUNK * D_))[tid];

        // ---- input projection [16,128]x[128,512], bias folded ----
        {
            f16x8 ax[4];
            #pragma unroll
            for (int kk = 0; kk < 4; kk++)
                ax[kk] = *(const f16x8*)&x_lds[l15][kk * 32 + lg * 8];
            f32x4 pacc[4] = {{0,0,0,0},{0,0,0,0},{0,0,0,0},{0,0,0,0}};
            #pragma unroll
            for (int q = 0; q < 4; q++)
                #pragma unroll
                for (int kk = 0; kk < 4; kk++)
                    pacc[q] = __builtin_amdgcn_mfma_f32_16x16x32_f16(
                        ax[kk], wbi[q][kk], pacc[q], 0, 0, 0);
            #pragma unroll
            for (int r = 0; r < 4; r++) {
                f32x4 row = { pacc[0][r] + bias[0], pacc[1][r] + bias[1],
                              pacc[2][r] + bias[2], pacc[3][r] + bias[3] };
                *(f32x4*)&proj_lds[lg * 4 + r][jw][0] = row;
            }
        }
        __syncthreads();

        // ---- 16 recurrence steps ----
        #pragma unroll 8
        for (int tt = 0; tt < CHUNK; tt++) {
            const f32x4 seed4 = *(const f32x4*)&proj_lds[tt][jw][0];

            f16x8 ah[4];
            const f16* hb2 = h2[tt & 1];
            #pragma unroll
            for (int kk = 0; kk < 4; kk++)
                ah[kk] = *(const f16x8*)&hb2[kk * 32 + lg * 8];

            float gate[4];
            #pragma unroll
            for (int q = 0; q < 4; q++) {
                // two independent chains of 2 (C rows 1..3 unread -> seed {s,0,0,0})
                f32x4 ca = { seed4[q], 0.f, 0.f, 0.f };
                ca = __builtin_amdgcn_mfma_f32_16x16x32_f16(ah[0], wbh[q][0], ca, 0, 0, 0);
                ca = __builtin_amdgcn_mfma_f32_16x16x32_f16(ah[1], wbh[q][1], ca, 0, 0, 0);
                f32x4 cb = { 0.f, 0.f, 0.f, 0.f };
                cb = __builtin_amdgcn_mfma_f32_16x16x32_f16(ah[2], wbh[q][2], cb, 0, 0, 0);
                cb = __builtin_amdgcn_mfma_f32_16x16x32_f16(ah[3], wbh[q][3], cb, 0, 0, 0);
                gate[q] = ca[0] + cb[0];
            }

            const float ig = sigf(gate[0]);
            const float fg = sigf(gate[1]);
            const float gt = tanh_fast(gate[2]);
            const float og = sigf(gate[3]);
            cst = fg * cst + ig * gt;
            const float h = og * tanh_fast(cst);

            if (lg == 0) {  // ds_write_b16; byte-enable merge, 2-way = free
                const f16 hf = (f16)h;
                h2[(tt + 1) & 1][jw] = hf;
                hbuf[tt][jw] = hf;
            }
            __syncthreads();
        }
    }
    // store final chunk's h
    {
        f16x4 hb = ((const f16x4*)hbuf)[tid];
        *(f16x4*)(hs + (size_t)(NCHUNK - 1) * CHUNK * H_ + (size_t)tid * 4) = hb;
    }
}

// ============================ attention ============================
__global__ __launch_bounds__(512)
void attention(const f16* __restrict__ h_states,  // [B,T,H] f16
               float* __restrict__ out) {         // [B,H]
    const int b   = blockIdx.x;
    const int tid = threadIdx.x;

    __shared__ float h_lds[H_];
    __shared__ float sc[T_];
    __shared__ float red[16];
    __shared__ float part[8][H_];

    const f16* hs = h_states + (size_t)b * T_ * H_;
    if (tid < H_) h_lds[tid] = (float)hs[(size_t)(T_ - 1) * H_ + tid];
    __syncthreads();

    // 1) scores: thread handles rows t = q*512 + tid
    #pragma unroll 1
    for (int q = 0; q < 4; q++) {
        const int t = q * 512 + tid;
        const f16x8* hr = (const f16x8*)(hs + (size_t)t * H_);
        float a0 = 0.f, a1 = 0.f;
        #pragma unroll
        for (int i = 0; i < 16; i++) {
            f16x8 v = hr[i];
            a0 += (float)v[0] * h_lds[i*8+0] + (float)v[1] * h_lds[i*8+1]
                + (float)v[2] * h_lds[i*8+2] + (float)v[3] * h_lds[i*8+3];
            a1 += (float)v[4] * h_lds[i*8+4] + (float)v[5] * h_lds[i*8+5]
                + (float)v[6] * h_lds[i*8+6] + (float)v[7] * h_lds[i*8+7];
        }
        sc[t] = a0 + a1;
    }
    __syncthreads();

    // 2) softmax over T
    float m = -3.0e38f;
    #pragma unroll
    for (int q = 0; q < 4; q++) m = fmaxf(m, sc[q * 512 + tid]);
    #pragma unroll
    for (int off = 1; off < 64; off <<= 1) m = fmaxf(m, __shfl_xor(m, off));
    if ((tid & 63) == 0) red[tid >> 6] = m;
    __syncthreads();
    float mx = red[0];
    #pragma unroll
    for (int w2 = 1; w2 < 8; w2++) mx = fmaxf(mx, red[w2]);

    float ssum = 0.f;
    #pragma unroll
    for (int q = 0; q < 4; q++) {
        float e = __expf(sc[q * 512 + tid] - mx);
        sc[q * 512 + tid] = e;
        ssum += e;
    }
    #pragma unroll
    for (int off = 1; off < 64; off <<= 1) ssum += __shfl_xor(ssum, off);
    if ((tid & 63) == 0) red[8 + (tid >> 6)] = ssum;
    __syncthreads();
    float tot = 0.f;
    #pragma unroll
    for (int w2 = 0; w2 < 8; w2++) tot += red[8 + w2];
    const float inv = 1.0f / tot;

    // 3) weighted sum: 8 row-groups of 256 t each; thread owns 2 cols
    {
        const int j2 = (tid & 63) * 2;
        const int qq = tid >> 6;
        const f16* base = hs + (size_t)qq * 256 * H_ + j2;
        const float* scp = sc + qq * 256;
        float a0 = 0.f, a1 = 0.f;
        #pragma unroll 4
        for (int t = 0; t < 256; t++) {
            f16x2 v = *(const f16x2*)(base + (size_t)t * H_);
            const float wgt = scp[t];
            a0 += wgt * (float)v[0];
            a1 += wgt * (float)v[1];
        }
        *(f32x2*)&part[qq][j2] = (f32x2){ a0, a1 };
    }
    __syncthreads();
    if (tid < H_) {
        float s = 0.f;
        #pragma unroll
        for (int qq = 0; qq < 8; qq++) s += part[qq][tid];
        out[(size_t)b * H_ + tid] = s * inv;
    }
}

extern "C" void kernel_launch(void* const* d_in, const int* in_sizes, int n_in,
                              void* d_out, int out_size, void* d_ws, size_t ws_size,
                              hipStream_t stream) {
    const float* x    = (const float*)d_in[0];
    const float* W_ih = (const float*)d_in[1];
    const float* W_hh = (const float*)d_in[2];
    const float* b_ih = (const float*)d_in[3];
    const float* b_hh = (const float*)d_in[4];
    float* out = (float*)d_out;

    f16* hs16 = (f16*)d_ws;                                     // 128 MB
    f16* pih  = (f16*)((char*)d_ws + (size_t)B_ * T_ * H_ * 2); // 128 KB
    f16* phh  = pih + 8192 * 8;                                 // 128 KB

    pack_weights<<<64, 256, 0, stream>>>(W_ih, W_hh, pih, phh);
    lstm_scan<<<B_, 512, 0, stream>>>(x, pih, phh, b_ih, b_hh, hs16);
    attention<<<B_, 512, 0, stream>>>(hs16, out);
}